// Round 2
// baseline (2567.230 us; speedup 1.0000x reference)
//
#include <hip/hip_runtime.h>
#include <math.h>

#define BSZ 4
#define TLEN 2048
#define DDIM 1024
#define NH 16
#define HDIM 64
#define NKOPS 4
#define RDIM 48
#define HR 768     // NH*RDIM
#define HHD 1024   // NH*HDIM
#define LNEPS 1e-5f

static __device__ __forceinline__ int clamp_pl(int p) {
    if (p < 1) p = 1;
    if (p > TLEN - 1) p = TLEN - 1;
    return p;
}

// ---------------- LayerNorm ----------------
__global__ __launch_bounds__(256) void ln_kernel(const float* __restrict__ hs,
                                                 const float* __restrict__ g,
                                                 const float* __restrict__ b,
                                                 float* __restrict__ out)
{
    int row = blockIdx.x;
    int tid = threadIdx.x;
    const float* x = hs + (size_t)row * DDIM;
    float4 v = ((const float4*)x)[tid];
    float s  = v.x + v.y + v.z + v.w;
    float ss = v.x*v.x + v.y*v.y + v.z*v.z + v.w*v.w;
    for (int off = 32; off > 0; off >>= 1) {
        s  += __shfl_down(s, off);
        ss += __shfl_down(ss, off);
    }
    __shared__ float rs[4], rss[4], st[2];
    int wid = tid >> 6, lane = tid & 63;
    if (lane == 0) { rs[wid] = s; rss[wid] = ss; }
    __syncthreads();
    if (tid == 0) {
        float S  = rs[0] + rs[1] + rs[2] + rs[3];
        float SS = rss[0] + rss[1] + rss[2] + rss[3];
        float mu = S / (float)DDIM;
        float var = SS / (float)DDIM - mu * mu;
        st[0] = mu;
        st[1] = rsqrtf(var + LNEPS);
    }
    __syncthreads();
    float mu = st[0], rstd = st[1];
    float4 gv = ((const float4*)g)[tid];
    float4 bv = ((const float4*)b)[tid];
    float4 o;
    o.x = (v.x - mu) * rstd * gv.x + bv.x;
    o.y = (v.y - mu) * rstd * gv.y + bv.y;
    o.z = (v.z - mu) * rstd * gv.z + bv.z;
    o.w = (v.w - mu) * rstd * gv.w + bv.w;
    ((float4*)(out + (size_t)row * DDIM))[tid] = o;
}

// ---------------- f32 GEMM: C[z] = A[z] @ B[z], 128x128 tile, BK=16, 8x8 micro ----------------
// Requires M,N divisible by 128 (true for all call sites), K divisible by 16.
// pl_ptr: clamp effective M (blocks beyond exit). gate_ptr: C *= sigmoid(*gate_ptr).
__global__ __launch_bounds__(256) void gemm128(const float* __restrict__ A, long sAz,
                                               const float* __restrict__ Bm, long sBz,
                                               float* __restrict__ C, long sCz,
                                               int M, int N, int K,
                                               const int* __restrict__ pl_ptr,
                                               const float* __restrict__ gate_ptr)
{
    int z = blockIdx.z;
    A  += (long)z * sAz;
    Bm += (long)z * sBz;
    C  += (long)z * sCz;
    int n0 = blockIdx.x * 128, m0 = blockIdx.y * 128;
    if (pl_ptr) {
        int p = clamp_pl(pl_ptr[0]);
        int Meff = p < M ? p : M;
        if (m0 >= Meff) return;
    }

    __shared__ float As[16][132];   // transposed: As[k][m]
    __shared__ float Bs[16][128];

    int tid = threadIdx.x;
    int tx = tid & 15, ty = tid >> 4;
    // A load: row = tid>>1 (0..127), kcol = (tid&1)*8
    int arow = tid >> 1, akc = (tid & 1) * 8;
    // B load: k = tid>>4 (0..15), ncol = (tid&15)*8
    int bk = tid >> 4, bn = (tid & 15) * 8;

    const float* Ap = A + (long)(m0 + arow) * K + akc;
    const float* Bp = Bm + (long)bk * N + n0 + bn;

    float acc[8][8] = {};

    for (int k0 = 0; k0 < K; k0 += 16) {
        float4 a0 = *(const float4*)(Ap + 0);
        float4 a1 = *(const float4*)(Ap + 4);
        float4 b0 = *(const float4*)(Bp + 0);
        float4 b1 = *(const float4*)(Bp + 4);
        Ap += 16;
        Bp += (long)16 * N;
        As[akc + 0][arow] = a0.x;
        As[akc + 1][arow] = a0.y;
        As[akc + 2][arow] = a0.z;
        As[akc + 3][arow] = a0.w;
        As[akc + 4][arow] = a1.x;
        As[akc + 5][arow] = a1.y;
        As[akc + 6][arow] = a1.z;
        As[akc + 7][arow] = a1.w;
        *(float4*)&Bs[bk][bn]     = b0;
        *(float4*)&Bs[bk][bn + 4] = b1;
        __syncthreads();
#pragma unroll
        for (int kk = 0; kk < 16; ++kk) {
            float4 av0 = *(const float4*)&As[kk][ty * 8];
            float4 av1 = *(const float4*)&As[kk][ty * 8 + 4];
            float4 bv0 = *(const float4*)&Bs[kk][tx * 8];
            float4 bv1 = *(const float4*)&Bs[kk][tx * 8 + 4];
            float a[8] = { av0.x, av0.y, av0.z, av0.w, av1.x, av1.y, av1.z, av1.w };
            float b[8] = { bv0.x, bv0.y, bv0.z, bv0.w, bv1.x, bv1.y, bv1.z, bv1.w };
#pragma unroll
            for (int i = 0; i < 8; ++i)
#pragma unroll
                for (int j = 0; j < 8; ++j)
                    acc[i][j] += a[i] * b[j];
        }
        __syncthreads();
    }

    float scale = 1.0f;
    if (gate_ptr) scale = 1.0f / (1.0f + expf(-gate_ptr[0]));
#pragma unroll
    for (int i = 0; i < 8; ++i) {
        float* Crow = C + (long)(m0 + ty * 8 + i) * N + n0 + tx * 8;
        float4 o0, o1;
        o0.x = acc[i][0] * scale; o0.y = acc[i][1] * scale;
        o0.z = acc[i][2] * scale; o0.w = acc[i][3] * scale;
        o1.x = acc[i][4] * scale; o1.y = acc[i][5] * scale;
        o1.z = acc[i][6] * scale; o1.w = acc[i][7] * scale;
        *(float4*)(Crow + 0) = o0;
        *(float4*)(Crow + 4) = o1;
    }
}

// ---------------- Gram statistics: G, M, Cv per (k,b,h) ----------------
__global__ __launch_bounds__(256) void gram_kernel(const float* __restrict__ Kp,
                                                   const float* __restrict__ Vp,
                                                   float* __restrict__ Gb,
                                                   float* __restrict__ Mb,
                                                   float* __restrict__ Cb,
                                                   int k, const int* __restrict__ pl_ptr)
{
    int h = blockIdx.x, b = blockIdx.y;
    int pl = clamp_pl(pl_ptr[0]);
    __shared__ float pks[65][48];
    __shared__ float pvs[64][64];
    int tid = threadIdx.x;
    int tx = tid & 15, ty = tid >> 4;
    float gacc[3][3] = {}, macc[3][3] = {}, cacc[4][3] = {};
    const float* Kbase = Kp + (size_t)b * TLEN * HR + h * RDIM;
    const float* Vbase = Vp + (size_t)b * TLEN * HHD + h * HDIM;

    for (int c0 = 0; c0 < pl; c0 += 64) {
        for (int idx = tid; idx < 65 * 48; idx += 256) {
            int rr = idx / 48, cc = idx % 48;
            int tg = c0 + rr;
            pks[rr][cc] = (tg < pl) ? Kbase[(size_t)tg * HR + cc] : 0.f;
        }
        for (int idx = tid; idx < 64 * 64; idx += 256) {
            int rr = idx >> 6, cc = idx & 63;
            int tg = c0 + rr;
            pvs[rr][cc] = (tg < pl) ? Vbase[(size_t)tg * HHD + cc] : 0.f;
        }
        __syncthreads();
#pragma unroll 2
        for (int l = 0; l < 64; ++l) {
            float a0[3], a1[3], bb[3], vv[4];
#pragma unroll
            for (int i = 0; i < 3; ++i) {
                a0[i] = pks[l][tx * 3 + i];
                a1[i] = pks[l + 1][tx * 3 + i];
                bb[i] = pks[l][ty * 3 + i];
            }
#pragma unroll
            for (int j = 0; j < 4; ++j) vv[j] = pvs[l][ty * 4 + j];
#pragma unroll
            for (int i = 0; i < 3; ++i)
#pragma unroll
                for (int j = 0; j < 3; ++j) {
                    gacc[i][j] += a0[i] * bb[j];
                    macc[i][j] += a1[i] * bb[j];
                }
#pragma unroll
            for (int j = 0; j < 4; ++j)
#pragma unroll
                for (int i = 0; i < 3; ++i)
                    cacc[j][i] += vv[j] * a0[i];
        }
        __syncthreads();
    }
    size_t base = ((size_t)(k * BSZ + b) * NH + h);
    float* Gp = Gb + base * 2304;
    float* Mp = Mb + base * 2304;
    float* Cp = Cb + base * 3072;
#pragma unroll
    for (int i = 0; i < 3; ++i)
#pragma unroll
        for (int j = 0; j < 3; ++j) {
            Gp[(tx * 3 + i) * 48 + (ty * 3 + j)] = gacc[i][j];
            Mp[(tx * 3 + i) * 48 + (ty * 3 + j)] = macc[i][j];
        }
#pragma unroll
    for (int j = 0; j < 4; ++j)
#pragma unroll
        for (int i = 0; i < 3; ++i)
            Cp[(ty * 4 + j) * 48 + (tx * 3 + i)] = cacc[j][i];
}

// ---------------- per-(k,b,h) solver, 256 threads ----------------
// F = B_v * L * A_w * A_w * L^{-1}   (64 x 48)
__global__ __launch_bounds__(256) void solver_kernel(const float* __restrict__ Gb,
                                                     const float* __restrict__ Mb,
                                                     const float* __restrict__ Cb,
                                                     float* __restrict__ Fb,
                                                     const float* __restrict__ log_ridges,
                                                     const float* __restrict__ log_gammas)
{
    int blk = blockIdx.x;                 // (k*BSZ + b)*NH + h
    int k = blk / (BSZ * NH);
    int t = threadIdx.x;
    __shared__ float Ls[48 * 49];
    __shared__ float Aw[48 * 49];
    __shared__ float Tw[48 * 49];         // scratch; aliased as S for power iteration
    __shared__ float Xs[48 * 65];         // B_v columns; later reused flat as 64x48
    __shared__ float B2[64 * 49];
    __shared__ float pv1[48], pv2[48], sred[1];
    float* Sm = Tw;

    size_t base = (size_t)blk;
    const float* Gp = Gb + base * 2304;
    const float* Mp = Mb + base * 2304;
    const float* Cp = Cb + base * 3072;
    float ridge = expf(log_ridges[k]);

    // load G + ridge*I
    for (int idx = t; idx < 2304; idx += 256) {
        int i = idx / 48, j = idx % 48;
        float v = Gp[idx];
        if (i == j) v += ridge;
        Ls[i * 49 + j] = v;
    }
    __syncthreads();
    // in-place lower Cholesky
    for (int j = 0; j < 48; ++j) {
        if (t == 0) {
            float d = Ls[j * 49 + j];
            for (int m = 0; m < j; ++m) d -= Ls[j * 49 + m] * Ls[j * 49 + m];
            Ls[j * 49 + j] = sqrtf(fmaxf(d, 1e-30f));
        }
        __syncthreads();
        if (t > j && t < 48) {
            float v = Ls[t * 49 + j];
            for (int m = 0; m < j; ++m) v -= Ls[t * 49 + m] * Ls[j * 49 + m];
            Ls[t * 49 + j] = v / Ls[j * 49 + j];
        }
        __syncthreads();
    }
    // U = L^{-1} M  (into Aw), column t per thread
    for (int idx = t; idx < 2304; idx += 256) Aw[(idx / 48) * 49 + (idx % 48)] = Mp[idx];
    __syncthreads();
    if (t < 48) {
        for (int i = 0; i < 48; ++i) {
            float v = Aw[i * 49 + t];
            for (int m = 0; m < i; ++m) v -= Ls[i * 49 + m] * Aw[m * 49 + t];
            Aw[i * 49 + t] = v / Ls[i * 49 + i];
        }
    }
    __syncthreads();
    // Tw = U^T ; Tw <- L^{-1} Tw ; Aw = Tw^T
    for (int idx = t; idx < 2304; idx += 256) { int i = idx / 48, j = idx % 48; Tw[i * 49 + j] = Aw[j * 49 + i]; }
    __syncthreads();
    if (t < 48) {
        for (int i = 0; i < 48; ++i) {
            float v = Tw[i * 49 + t];
            for (int m = 0; m < i; ++m) v -= Ls[i * 49 + m] * Tw[m * 49 + t];
            Tw[i * 49 + t] = v / Ls[i * 49 + i];
        }
    }
    __syncthreads();
    for (int idx = t; idx < 2304; idx += 256) { int i = idx / 48, j = idx % 48; Aw[i * 49 + j] = Tw[j * 49 + i]; }
    __syncthreads();
    // S = Aw^T Aw (into Sm == Tw)
    for (int idx = t; idx < 2304; idx += 256) {
        int i = idx / 48, j = idx % 48;
        float s = 0.f;
        for (int m = 0; m < 48; ++m) s += Aw[m * 49 + i] * Aw[m * 49 + j];
        Sm[i * 49 + j] = s;
    }
    // power iteration on S: sigma^2 = lambda_max(S)
    if (t < 48) pv1[t] = ((float)((t * 2654435761u) & 0xFFFF)) / 65536.0f + 0.5f;
    __syncthreads();
    for (int it = 0; it < 96; ++it) {
        if (t < 48) {
            float s = 0.f;
            for (int j = 0; j < 48; ++j) s += Sm[t * 49 + j] * pv1[j];
            pv2[t] = s;
        }
        __syncthreads();
        if (t < 48) {
            float n = 0.f;
            for (int j = 0; j < 48; ++j) n += pv2[j] * pv2[j];
            pv1[t] = pv2[t] * rsqrtf(fmaxf(n, 1e-30f));
        }
        __syncthreads();
    }
    if (t < 48) {
        float s = 0.f;
        for (int j = 0; j < 48; ++j) s += Sm[t * 49 + j] * pv1[j];
        pv2[t] = s;
    }
    __syncthreads();
    if (t == 0) {
        float n = 0.f;
        for (int j = 0; j < 48; ++j) n += pv2[j] * pv2[j];
        float lam = sqrtf(n);               // lambda_max(S)
        float sigma = sqrtf(fmaxf(lam, 0.f));
        float gamma = expf(log_gammas[k]);
        sred[0] = fminf(gamma, 1.f) / fmaxf(fmaxf(sigma, 1e-8f), 1.f);
    }
    __syncthreads();
    {
        float scl = sred[0];
        for (int idx = t; idx < 2304; idx += 256) { int i = idx / 48, j = idx % 48; Aw[i * 49 + j] *= scl; }
    }
    __syncthreads();
    // Bv^T = L^{-T} L^{-1} Cv^T   (Xs[r*65+d], 64 columns, one per thread t<64)
    for (int idx = t; idx < 3072; idx += 256) {
        int d = idx / 48, r = idx % 48;
        Xs[r * 65 + d] = Cp[idx];
    }
    __syncthreads();
    if (t < 64) {
        for (int i = 0; i < 48; ++i) {
            float v = Xs[i * 65 + t];
            for (int m = 0; m < i; ++m) v -= Ls[i * 49 + m] * Xs[m * 65 + t];
            Xs[i * 65 + t] = v / Ls[i * 49 + i];
        }
        for (int i = 47; i >= 0; --i) {
            float v = Xs[i * 65 + t];
            for (int m = i + 1; m < 48; ++m) v -= Ls[m * 49 + i] * Xs[m * 65 + t];
            Xs[i * 65 + t] = v / Ls[i * 49 + i];
        }
    }
    __syncthreads();
    // T1 = B_v * L  -> B2[d*49+j]   (B_v[d][m] = Xs[m*65+d])
    for (int idx = t; idx < 3072; idx += 256) {
        int d = idx / 48, j = idx % 48;
        float s = 0.f;
        for (int m = j; m < 48; ++m) s += Xs[m * 65 + d] * Ls[m * 49 + j];
        B2[d * 49 + j] = s;
    }
    __syncthreads();
    // T2 = T1 * Aw -> Xs flat [d*48+j]
    for (int idx = t; idx < 3072; idx += 256) {
        int d = idx / 48, j = idx % 48;
        float s = 0.f;
        for (int m = 0; m < 48; ++m) s += B2[d * 49 + m] * Aw[m * 49 + j];
        Xs[d * 48 + j] = s;
    }
    __syncthreads();
    // T3 = T2 * Aw -> B2
    for (int idx = t; idx < 3072; idx += 256) {
        int d = idx / 48, j = idx % 48;
        float s = 0.f;
        for (int m = 0; m < 48; ++m) s += Xs[d * 48 + m] * Aw[m * 49 + j];
        B2[d * 49 + j] = s;
    }
    __syncthreads();
    // F solves F*L = T3, row d per thread (t<64), into Xs flat
    if (t < 64) {
        int d = t;
        for (int j = 47; j >= 0; --j) {
            float s = B2[d * 49 + j];
            for (int m = j + 1; m < 48; ++m) s -= Xs[d * 48 + m] * Ls[m * 49 + j];
            Xs[d * 48 + j] = s / Ls[j * 49 + j];
        }
    }
    __syncthreads();
    for (int idx = t; idx < 3072; idx += 256) Fb[base * 3072 + idx] = Xs[idx];
}

// ---------------- W_cmb build ----------------
__global__ __launch_bounds__(256) void wcmb_kernel(const float* __restrict__ WQ,
                                                   const float* __restrict__ Fb,
                                                   const float* __restrict__ gate_alphas,
                                                   float* __restrict__ Wcmb)
{
    int dt = blockIdx.x;  // row tile (0..15)
    int h = blockIdx.y, b = blockIdx.z;
    __shared__ float wq[64][49];
    __shared__ float fs[64][49];
    int tid = threadIdx.x;
    int tx = tid & 15, ty = tid >> 4;
    float acc[4][4] = {};
    for (int k = 0; k < NKOPS; ++k) {
        float gate = 1.0f / (1.0f + expf(-gate_alphas[k]));
        for (int idx = tid; idx < 64 * 48; idx += 256) {
            int rr = idx / 48, cc = idx % 48;
            wq[rr][cc] = WQ[((size_t)k * DDIM + dt * 64 + rr) * HR + h * RDIM + cc];
            fs[rr][cc] = gate * Fb[(((size_t)k * BSZ + b) * NH + h) * 3072 + idx];
        }
        __syncthreads();
        for (int r = 0; r < 48; ++r) {
            float a[4], bb[4];
#pragma unroll
            for (int i = 0; i < 4; ++i) { a[i] = wq[tx * 4 + i][r]; bb[i] = fs[ty * 4 + i][r]; }
#pragma unroll
            for (int i = 0; i < 4; ++i)
#pragma unroll
                for (int j = 0; j < 4; ++j)
                    acc[i][j] += a[i] * bb[j];
        }
        __syncthreads();
    }
#pragma unroll
    for (int i = 0; i < 4; ++i)
#pragma unroll
        for (int j = 0; j < 4; ++j)
            Wcmb[((size_t)b * DDIM + dt * 64 + tx * 4 + i) * HHD + h * HDIM + ty * 4 + j] = acc[i][j];
}

// ---------------- host launch ----------------
extern "C" void kernel_launch(void* const* d_in, const int* in_sizes, int n_in,
                              void* d_out, int out_size, void* d_ws, size_t ws_size,
                              hipStream_t stream)
{
    const float* hs          = (const float*)d_in[0];
    const float* WK          = (const float*)d_in[1];
    const float* WQ          = (const float*)d_in[2];
    const float* WV          = (const float*)d_in[3];
    const float* WO          = (const float*)d_in[4];
    const float* ln_g        = (const float*)d_in[5];
    const float* ln_b        = (const float*)d_in[6];
    const float* gate_alphas = (const float*)d_in[7];
    const float* gate_alpha  = (const float*)d_in[8];
    const float* log_ridges  = (const float*)d_in[9];
    const float* log_gammas  = (const float*)d_in[10];
    const int*   pl_ptr      = (const int*)d_in[11];
    float* out = (float*)d_out;

    float* ws = (float*)d_ws;
    float* normed = ws;                       // 8388608
    float* Vp     = normed + 8388608;         // 8388608
    float* Kp     = Vp + 8388608;             // 6291456
    float* Gb     = Kp + 6291456;             // 589824
    float* Mb     = Gb + 589824;              // 589824
    float* Cb     = Mb + 589824;              // 786432
    float* Fb     = Cb + 786432;              // 786432
    float* Wcmb   = Vp;                       // alias: Vp dead after grams
    float* Wfin   = Kp;                       // alias: Kp dead after grams

    ln_kernel<<<BSZ * TLEN, 256, 0, stream>>>(hs, ln_g, ln_b, normed);

    // Vp = normed_prefix @ WV   (per b)
    gemm128<<<dim3(HHD / 128, TLEN / 128, BSZ), 256, 0, stream>>>(
        normed, (long)TLEN * DDIM, WV, 0, Vp, (long)TLEN * HHD,
        TLEN, HHD, DDIM, pl_ptr, nullptr);

    for (int k = 0; k < NKOPS; ++k) {
        gemm128<<<dim3(HR / 128, TLEN / 128, BSZ), 256, 0, stream>>>(
            normed, (long)TLEN * DDIM, WK + (size_t)k * DDIM * HR, 0, Kp, (long)TLEN * HR,
            TLEN, HR, DDIM, pl_ptr, nullptr);
        gram_kernel<<<dim3(NH, BSZ), 256, 0, stream>>>(Kp, Vp, Gb, Mb, Cb, k, pl_ptr);
    }

    solver_kernel<<<NKOPS * BSZ * NH, 256, 0, stream>>>(Gb, Mb, Cb, Fb, log_ridges, log_gammas);

    wcmb_kernel<<<dim3(DDIM / 64, NH, BSZ), 256, 0, stream>>>(WQ, Fb, gate_alphas, Wcmb);

    // Wfin[b] = Wcmb[b] @ WO
    gemm128<<<dim3(DDIM / 128, DDIM / 128, BSZ), 256, 0, stream>>>(
        Wcmb, (long)DDIM * HHD, WO, 0, Wfin, (long)DDIM * DDIM,
        DDIM, DDIM, HHD, nullptr, nullptr);

    // out[b] = sigmoid(gate_alpha) * normed[b] @ Wfin[b]
    gemm128<<<dim3(DDIM / 128, TLEN / 128, BSZ), 256, 0, stream>>>(
        normed, (long)TLEN * DDIM, Wfin, (long)DDIM * DDIM, out, (long)TLEN * DDIM,
        TLEN, DDIM, DDIM, nullptr, gate_alpha);
}

// Round 3
// 1606.944 us; speedup vs baseline: 1.5976x; 1.5976x over previous
//
#include <hip/hip_runtime.h>
#include <math.h>

typedef unsigned short u16;
typedef __attribute__((ext_vector_type(8))) short bf16x8;
typedef __attribute__((ext_vector_type(4))) float f32x4;

#define BSZ 4
#define TLEN 2048
#define DDIM 1024
#define NH 16
#define HDIM 64
#define NKOPS 4
#define RDIM 48
#define HR 768     // NH*RDIM
#define HHD 1024   // NH*HDIM
#define LNEPS 1e-5f

static __device__ __forceinline__ int clamp_pl(int p) {
    if (p < 1) p = 1;
    if (p > TLEN - 1) p = TLEN - 1;
    return p;
}

static __device__ __forceinline__ u16 f2bf(float x) {
    unsigned u = __float_as_uint(x);
    return (u16)((u + 0x7FFFu + ((u >> 16) & 1u)) >> 16);
}
static __device__ __forceinline__ float bf2f(u16 h) {
    return __uint_as_float(((unsigned)h) << 16);
}

// ---------------- LayerNorm -> bf16 hi/lo split ----------------
__global__ __launch_bounds__(256) void ln_kernel(const float* __restrict__ hs,
                                                 const float* __restrict__ g,
                                                 const float* __restrict__ b,
                                                 u16* __restrict__ nh,
                                                 u16* __restrict__ nl)
{
    int row = blockIdx.x;
    int tid = threadIdx.x;
    const float* x = hs + (size_t)row * DDIM;
    float4 v = ((const float4*)x)[tid];
    float s  = v.x + v.y + v.z + v.w;
    float ss = v.x*v.x + v.y*v.y + v.z*v.z + v.w*v.w;
    for (int off = 32; off > 0; off >>= 1) {
        s  += __shfl_down(s, off);
        ss += __shfl_down(ss, off);
    }
    __shared__ float rs[4], rss[4], st[2];
    int wid = tid >> 6, lane = tid & 63;
    if (lane == 0) { rs[wid] = s; rss[wid] = ss; }
    __syncthreads();
    if (tid == 0) {
        float S  = rs[0] + rs[1] + rs[2] + rs[3];
        float SS = rss[0] + rss[1] + rss[2] + rss[3];
        float mu = S / (float)DDIM;
        float var = SS / (float)DDIM - mu * mu;
        st[0] = mu;
        st[1] = rsqrtf(var + LNEPS);
    }
    __syncthreads();
    float mu = st[0], rstd = st[1];
    float4 gv = ((const float4*)g)[tid];
    float4 bv = ((const float4*)b)[tid];
    float o[4];
    o[0] = (v.x - mu) * rstd * gv.x + bv.x;
    o[1] = (v.y - mu) * rstd * gv.y + bv.y;
    o[2] = (v.z - mu) * rstd * gv.z + bv.z;
    o[3] = (v.w - mu) * rstd * gv.w + bv.w;
    u16 h[4], l[4];
#pragma unroll
    for (int i = 0; i < 4; ++i) {
        h[i] = f2bf(o[i]);
        l[i] = f2bf(o[i] - bf2f(h[i]));
    }
    uint2 ph, pl2;
    ph.x = (unsigned)h[0] | ((unsigned)h[1] << 16);
    ph.y = (unsigned)h[2] | ((unsigned)h[3] << 16);
    pl2.x = (unsigned)l[0] | ((unsigned)l[1] << 16);
    pl2.y = (unsigned)l[2] | ((unsigned)l[3] << 16);
    *(uint2*)(nh + (size_t)row * DDIM + tid * 4) = ph;
    *(uint2*)(nl + (size_t)row * DDIM + tid * 4) = pl2;
}

// ---------------- transpose + bf16 hi/lo convert: in[R][C] f32 -> out[C][R] ----------------
__global__ __launch_bounds__(256) void transcvt(const float* __restrict__ in,
                                                u16* __restrict__ oh,
                                                u16* __restrict__ ol,
                                                int R, int C)
{
    __shared__ float t[32][33];
    int bx = blockIdx.x, by = blockIdx.y;
    int tx = threadIdx.x & 31, ty = threadIdx.x >> 5;
#pragma unroll
    for (int j = 0; j < 4; ++j)
        t[ty + j * 8][tx] = in[(size_t)(by * 32 + ty + j * 8) * C + bx * 32 + tx];
    __syncthreads();
#pragma unroll
    for (int j = 0; j < 4; ++j) {
        float v = t[tx][ty + j * 8];
        u16 h = f2bf(v);
        size_t o = (size_t)(bx * 32 + ty + j * 8) * R + by * 32 + tx;
        oh[o] = h;
        ol[o] = f2bf(v - bf2f(h));
    }
}

// ---------------- split-bf16 MFMA GEMM (NT): C[z] = A[z] @ Bt[z]^T ----------------
// A: [M][K] bf16 hi/lo, Bt: [N][K] bf16 hi/lo. 128x128 tile, BK=32, 4 waves.
// OMODE 0: f32 C out (optional sigmoid(gate) scale). OMODE 1: bf16 hi/lo out (row-major).
template<int OMODE>
__global__ __launch_bounds__(256) void gemm_mfma(
    const u16* __restrict__ Ah, const u16* __restrict__ Al, long sAz,
    const u16* __restrict__ Bth, const u16* __restrict__ Btl, long sBz,
    float* __restrict__ C, u16* __restrict__ Oh, u16* __restrict__ Ol, long sCz,
    int M, int N, int K,
    const int* __restrict__ pl_ptr, const float* __restrict__ gate_ptr)
{
    int z = blockIdx.z;
    int m0 = blockIdx.y * 128, n0 = blockIdx.x * 128;
    if (pl_ptr) {
        int p = clamp_pl(pl_ptr[0]);
        if (m0 >= (p < M ? p : M)) return;
    }
    Ah  += (size_t)z * sAz;  Al  += (size_t)z * sAz;
    Bth += (size_t)z * sBz;  Btl += (size_t)z * sBz;

    __shared__ u16 As[2][128][40];   // [hi/lo][row][k], 80B row stride (16B-aligned, low conflicts)
    __shared__ u16 Bs[2][128][40];

    int tid = threadIdx.x;
    int wid = tid >> 6, ln = tid & 63;
    int wm = (wid >> 1) * 64, wn = (wid & 1) * 64;
    int r16 = ln & 15, kg = ln >> 4;

    // staging: thread -> row tid>>1, 16 consecutive bf16 at col (tid&1)*16
    int srow = tid >> 1, scol = (tid & 1) * 16;
    const u16* gAh = Ah  + (size_t)(m0 + srow) * K + scol;
    const u16* gAl = Al  + (size_t)(m0 + srow) * K + scol;
    const u16* gBh = Bth + (size_t)(n0 + srow) * K + scol;
    const u16* gBl = Btl + (size_t)(n0 + srow) * K + scol;

    f32x4 acc[4][4];
#pragma unroll
    for (int mt = 0; mt < 4; ++mt)
#pragma unroll
        for (int nt = 0; nt < 4; ++nt)
            acc[mt][nt] = (f32x4){0.f, 0.f, 0.f, 0.f};

    for (int k0 = 0; k0 < K; k0 += 32) {
        uint4 a0 = *(const uint4*)(gAh);  uint4 a1 = *(const uint4*)(gAh + 8);
        uint4 l0 = *(const uint4*)(gAl);  uint4 l1 = *(const uint4*)(gAl + 8);
        uint4 b0 = *(const uint4*)(gBh);  uint4 b1 = *(const uint4*)(gBh + 8);
        uint4 c0 = *(const uint4*)(gBl);  uint4 c1 = *(const uint4*)(gBl + 8);
        gAh += 32; gAl += 32; gBh += 32; gBl += 32;
        __syncthreads();                       // prior compute done reading LDS
        *(uint4*)&As[0][srow][scol]     = a0;
        *(uint4*)&As[0][srow][scol + 8] = a1;
        *(uint4*)&As[1][srow][scol]     = l0;
        *(uint4*)&As[1][srow][scol + 8] = l1;
        *(uint4*)&Bs[0][srow][scol]     = b0;
        *(uint4*)&Bs[0][srow][scol + 8] = b1;
        *(uint4*)&Bs[1][srow][scol]     = c0;
        *(uint4*)&Bs[1][srow][scol + 8] = c1;
        __syncthreads();

        bf16x8 bh[4], bl[4];
#pragma unroll
        for (int nt = 0; nt < 4; ++nt) {
            bh[nt] = *(const bf16x8*)&Bs[0][wn + nt * 16 + r16][kg * 8];
            bl[nt] = *(const bf16x8*)&Bs[1][wn + nt * 16 + r16][kg * 8];
        }
#pragma unroll
        for (int mt = 0; mt < 4; ++mt) {
            bf16x8 ah = *(const bf16x8*)&As[0][wm + mt * 16 + r16][kg * 8];
            bf16x8 al = *(const bf16x8*)&As[1][wm + mt * 16 + r16][kg * 8];
#pragma unroll
            for (int nt = 0; nt < 4; ++nt) {
                acc[mt][nt] = __builtin_amdgcn_mfma_f32_16x16x32_bf16(ah, bh[nt], acc[mt][nt], 0, 0, 0);
                acc[mt][nt] = __builtin_amdgcn_mfma_f32_16x16x32_bf16(ah, bl[nt], acc[mt][nt], 0, 0, 0);
                acc[mt][nt] = __builtin_amdgcn_mfma_f32_16x16x32_bf16(al, bh[nt], acc[mt][nt], 0, 0, 0);
            }
        }
    }

    // C/D layout (m89/m91-verified): col = lane&15, row = (lane>>4)*4 + reg
    int orow0 = m0 + wm + kg * 4;
    int ocol0 = n0 + wn + r16;
    if (OMODE == 0) {
        float scale = 1.0f;
        if (gate_ptr) scale = 1.0f / (1.0f + expf(-gate_ptr[0]));
        float* Cz = C + (size_t)z * sCz;
#pragma unroll
        for (int mt = 0; mt < 4; ++mt)
#pragma unroll
            for (int nt = 0; nt < 4; ++nt)
#pragma unroll
                for (int j = 0; j < 4; ++j)
                    Cz[(size_t)(orow0 + mt * 16 + j) * N + ocol0 + nt * 16] = acc[mt][nt][j] * scale;
    } else {
        u16* Ohz = Oh + (size_t)z * sCz;
        u16* Olz = Ol + (size_t)z * sCz;
#pragma unroll
        for (int mt = 0; mt < 4; ++mt)
#pragma unroll
            for (int nt = 0; nt < 4; ++nt)
#pragma unroll
                for (int j = 0; j < 4; ++j) {
                    float v = acc[mt][nt][j];
                    u16 h = f2bf(v);
                    size_t o = (size_t)(orow0 + mt * 16 + j) * N + ocol0 + nt * 16;
                    Ohz[o] = h;
                    Olz[o] = f2bf(v - bf2f(h));
                }
    }
}

// ---------------- Gram statistics: G, M, Cv per (k,b,h) ----------------
__global__ __launch_bounds__(256) void gram_kernel(const float* __restrict__ Kp,
                                                   const float* __restrict__ Vp,
                                                   float* __restrict__ Gb,
                                                   float* __restrict__ Mb,
                                                   float* __restrict__ Cb,
                                                   int k, const int* __restrict__ pl_ptr)
{
    int h = blockIdx.x, b = blockIdx.y;
    int pl = clamp_pl(pl_ptr[0]);
    __shared__ float pks[65][48];
    __shared__ float pvs[64][64];
    int tid = threadIdx.x;
    int tx = tid & 15, ty = tid >> 4;
    float gacc[3][3] = {}, macc[3][3] = {}, cacc[4][3] = {};
    const float* Kbase = Kp + (size_t)b * TLEN * HR + h * RDIM;
    const float* Vbase = Vp + (size_t)b * TLEN * HHD + h * HDIM;

    for (int c0 = 0; c0 < pl; c0 += 64) {
        for (int idx = tid; idx < 65 * 48; idx += 256) {
            int rr = idx / 48, cc = idx % 48;
            int tg = c0 + rr;
            pks[rr][cc] = (tg < pl) ? Kbase[(size_t)tg * HR + cc] : 0.f;
        }
        for (int idx = tid; idx < 64 * 64; idx += 256) {
            int rr = idx >> 6, cc = idx & 63;
            int tg = c0 + rr;
            pvs[rr][cc] = (tg < pl) ? Vbase[(size_t)tg * HHD + cc] : 0.f;
        }
        __syncthreads();
#pragma unroll 2
        for (int l = 0; l < 64; ++l) {
            float a0[3], a1[3], bb[3], vv[4];
#pragma unroll
            for (int i = 0; i < 3; ++i) {
                a0[i] = pks[l][tx * 3 + i];
                a1[i] = pks[l + 1][tx * 3 + i];
                bb[i] = pks[l][ty * 3 + i];
            }
#pragma unroll
            for (int j = 0; j < 4; ++j) vv[j] = pvs[l][ty * 4 + j];
#pragma unroll
            for (int i = 0; i < 3; ++i)
#pragma unroll
                for (int j = 0; j < 3; ++j) {
                    gacc[i][j] += a0[i] * bb[j];
                    macc[i][j] += a1[i] * bb[j];
                }
#pragma unroll
            for (int j = 0; j < 4; ++j)
#pragma unroll
                for (int i = 0; i < 3; ++i)
                    cacc[j][i] += vv[j] * a0[i];
        }
        __syncthreads();
    }
    size_t base = ((size_t)(k * BSZ + b) * NH + h);
    float* Gp = Gb + base * 2304;
    float* Mp = Mb + base * 2304;
    float* Cp = Cb + base * 3072;
#pragma unroll
    for (int i = 0; i < 3; ++i)
#pragma unroll
        for (int j = 0; j < 3; ++j) {
            Gp[(tx * 3 + i) * 48 + (ty * 3 + j)] = gacc[i][j];
            Mp[(tx * 3 + i) * 48 + (ty * 3 + j)] = macc[i][j];
        }
#pragma unroll
    for (int j = 0; j < 4; ++j)
#pragma unroll
        for (int i = 0; i < 3; ++i)
            Cp[(ty * 4 + j) * 48 + (tx * 3 + i)] = cacc[j][i];
}

// ---------------- per-(k,b,h) solver, 256 threads ----------------
__global__ __launch_bounds__(256) void solver_kernel(const float* __restrict__ Gb,
                                                     const float* __restrict__ Mb,
                                                     const float* __restrict__ Cb,
                                                     float* __restrict__ Fb,
                                                     const float* __restrict__ log_ridges,
                                                     const float* __restrict__ log_gammas)
{
    int blk = blockIdx.x;                 // (k*BSZ + b)*NH + h
    int k = blk / (BSZ * NH);
    int t = threadIdx.x;
    __shared__ float Ls[48 * 49];
    __shared__ float Aw[48 * 49];
    __shared__ float Tw[48 * 49];
    __shared__ float Xs[48 * 65];
    __shared__ float B2[64 * 49];
    __shared__ float pv1[48], pv2[48], sred[1];
    float* Sm = Tw;

    size_t base = (size_t)blk;
    const float* Gp = Gb + base * 2304;
    const float* Mp = Mb + base * 2304;
    const float* Cp = Cb + base * 3072;
    float ridge = expf(log_ridges[k]);

    for (int idx = t; idx < 2304; idx += 256) {
        int i = idx / 48, j = idx % 48;
        float v = Gp[idx];
        if (i == j) v += ridge;
        Ls[i * 49 + j] = v;
    }
    __syncthreads();
    for (int j = 0; j < 48; ++j) {
        if (t == 0) {
            float d = Ls[j * 49 + j];
            for (int m = 0; m < j; ++m) d -= Ls[j * 49 + m] * Ls[j * 49 + m];
            Ls[j * 49 + j] = sqrtf(fmaxf(d, 1e-30f));
        }
        __syncthreads();
        if (t > j && t < 48) {
            float v = Ls[t * 49 + j];
            for (int m = 0; m < j; ++m) v -= Ls[t * 49 + m] * Ls[j * 49 + m];
            Ls[t * 49 + j] = v / Ls[j * 49 + j];
        }
        __syncthreads();
    }
    for (int idx = t; idx < 2304; idx += 256) Aw[(idx / 48) * 49 + (idx % 48)] = Mp[idx];
    __syncthreads();
    if (t < 48) {
        for (int i = 0; i < 48; ++i) {
            float v = Aw[i * 49 + t];
            for (int m = 0; m < i; ++m) v -= Ls[i * 49 + m] * Aw[m * 49 + t];
            Aw[i * 49 + t] = v / Ls[i * 49 + i];
        }
    }
    __syncthreads();
    for (int idx = t; idx < 2304; idx += 256) { int i = idx / 48, j = idx % 48; Tw[i * 49 + j] = Aw[j * 49 + i]; }
    __syncthreads();
    if (t < 48) {
        for (int i = 0; i < 48; ++i) {
            float v = Tw[i * 49 + t];
            for (int m = 0; m < i; ++m) v -= Ls[i * 49 + m] * Tw[m * 49 + t];
            Tw[i * 49 + t] = v / Ls[i * 49 + i];
        }
    }
    __syncthreads();
    for (int idx = t; idx < 2304; idx += 256) { int i = idx / 48, j = idx % 48; Aw[i * 49 + j] = Tw[j * 49 + i]; }
    __syncthreads();
    for (int idx = t; idx < 2304; idx += 256) {
        int i = idx / 48, j = idx % 48;
        float s = 0.f;
        for (int m = 0; m < 48; ++m) s += Aw[m * 49 + i] * Aw[m * 49 + j];
        Sm[i * 49 + j] = s;
    }
    if (t < 48) pv1[t] = ((float)((t * 2654435761u) & 0xFFFF)) / 65536.0f + 0.5f;
    __syncthreads();
    for (int it = 0; it < 96; ++it) {
        if (t < 48) {
            float s = 0.f;
            for (int j = 0; j < 48; ++j) s += Sm[t * 49 + j] * pv1[j];
            pv2[t] = s;
        }
        __syncthreads();
        if (t < 48) {
            float n = 0.f;
            for (int j = 0; j < 48; ++j) n += pv2[j] * pv2[j];
            pv1[t] = pv2[t] * rsqrtf(fmaxf(n, 1e-30f));
        }
        __syncthreads();
    }
    if (t < 48) {
        float s = 0.f;
        for (int j = 0; j < 48; ++j) s += Sm[t * 49 + j] * pv1[j];
        pv2[t] = s;
    }
    __syncthreads();
    if (t == 0) {
        float n = 0.f;
        for (int j = 0; j < 48; ++j) n += pv2[j] * pv2[j];
        float lam = sqrtf(n);
        float sigma = sqrtf(fmaxf(lam, 0.f));
        float gamma = expf(log_gammas[k]);
        sred[0] = fminf(gamma, 1.f) / fmaxf(fmaxf(sigma, 1e-8f), 1.f);
    }
    __syncthreads();
    {
        float scl = sred[0];
        for (int idx = t; idx < 2304; idx += 256) { int i = idx / 48, j = idx % 48; Aw[i * 49 + j] *= scl; }
    }
    __syncthreads();
    for (int idx = t; idx < 3072; idx += 256) {
        int d = idx / 48, r = idx % 48;
        Xs[r * 65 + d] = Cp[idx];
    }
    __syncthreads();
    if (t < 64) {
        for (int i = 0; i < 48; ++i) {
            float v = Xs[i * 65 + t];
            for (int m = 0; m < i; ++m) v -= Ls[i * 49 + m] * Xs[m * 65 + t];
            Xs[i * 65 + t] = v / Ls[i * 49 + i];
        }
        for (int i = 47; i >= 0; --i) {
            float v = Xs[i * 65 + t];
            for (int m = i + 1; m < 48; ++m) v -= Ls[m * 49 + i] * Xs[m * 65 + t];
            Xs[i * 65 + t] = v / Ls[i * 49 + i];
        }
    }
    __syncthreads();
    for (int idx = t; idx < 3072; idx += 256) {
        int d = idx / 48, j = idx % 48;
        float s = 0.f;
        for (int m = j; m < 48; ++m) s += Xs[m * 65 + d] * Ls[m * 49 + j];
        B2[d * 49 + j] = s;
    }
    __syncthreads();
    for (int idx = t; idx < 3072; idx += 256) {
        int d = idx / 48, j = idx % 48;
        float s = 0.f;
        for (int m = 0; m < 48; ++m) s += B2[d * 49 + m] * Aw[m * 49 + j];
        Xs[d * 48 + j] = s;
    }
    __syncthreads();
    for (int idx = t; idx < 3072; idx += 256) {
        int d = idx / 48, j = idx % 48;
        float s = 0.f;
        for (int m = 0; m < 48; ++m) s += Xs[d * 48 + m] * Aw[m * 49 + j];
        B2[d * 49 + j] = s;
    }
    __syncthreads();
    if (t < 64) {
        int d = t;
        for (int j = 47; j >= 0; --j) {
            float s = B2[d * 49 + j];
            for (int m = j + 1; m < 48; ++m) s -= Xs[d * 48 + m] * Ls[m * 49 + j];
            Xs[d * 48 + j] = s / Ls[j * 49 + j];
        }
    }
    __syncthreads();
    for (int idx = t; idx < 3072; idx += 256) Fb[base * 3072 + idx] = Xs[idx];
}

// ---------------- W_cmb build -> bf16 hi/lo ----------------
__global__ __launch_bounds__(256) void wcmb_kernel(const float* __restrict__ WQ,
                                                   const float* __restrict__ Fb,
                                                   const float* __restrict__ gate_alphas,
                                                   u16* __restrict__ Wh,
                                                   u16* __restrict__ Wl)
{
    int dt = blockIdx.x;  // row tile (0..15)
    int h = blockIdx.y, b = blockIdx.z;
    __shared__ float wq[64][49];
    __shared__ float fs[64][49];
    int tid = threadIdx.x;
    int tx = tid & 15, ty = tid >> 4;
    float acc[4][4] = {};
    for (int k = 0; k < NKOPS; ++k) {
        float gate = 1.0f / (1.0f + expf(-gate_alphas[k]));
        for (int idx = tid; idx < 64 * 48; idx += 256) {
            int rr = idx / 48, cc = idx % 48;
            wq[rr][cc] = WQ[((size_t)k * DDIM + dt * 64 + rr) * HR + h * RDIM + cc];
            fs[rr][cc] = gate * Fb[(((size_t)k * BSZ + b) * NH + h) * 3072 + idx];
        }
        __syncthreads();
        for (int r = 0; r < 48; ++r) {
            float a[4], bb[4];
#pragma unroll
            for (int i = 0; i < 4; ++i) { a[i] = wq[tx * 4 + i][r]; bb[i] = fs[ty * 4 + i][r]; }
#pragma unroll
            for (int i = 0; i < 4; ++i)
#pragma unroll
                for (int j = 0; j < 4; ++j)
                    acc[i][j] += a[i] * bb[j];
        }
        __syncthreads();
    }
#pragma unroll
    for (int i = 0; i < 4; ++i)
#pragma unroll
        for (int j = 0; j < 4; ++j) {
            size_t o = ((size_t)b * DDIM + dt * 64 + tx * 4 + i) * HHD + h * HDIM + ty * 4 + j;
            float v = acc[i][j];
            u16 hh = f2bf(v);
            Wh[o] = hh;
            Wl[o] = f2bf(v - bf2f(hh));
        }
}

// ---------------- host launch ----------------
extern "C" void kernel_launch(void* const* d_in, const int* in_sizes, int n_in,
                              void* d_out, int out_size, void* d_ws, size_t ws_size,
                              hipStream_t stream)
{
    const float* hs          = (const float*)d_in[0];
    const float* WK          = (const float*)d_in[1];
    const float* WQ          = (const float*)d_in[2];
    const float* WV          = (const float*)d_in[3];
    const float* WO          = (const float*)d_in[4];
    const float* ln_g        = (const float*)d_in[5];
    const float* ln_b        = (const float*)d_in[6];
    const float* gate_alphas = (const float*)d_in[7];
    const float* gate_alpha  = (const float*)d_in[8];
    const float* log_ridges  = (const float*)d_in[9];
    const float* log_gammas  = (const float*)d_in[10];
    const int*   pl_ptr      = (const int*)d_in[11];
    float* out = (float*)d_out;

    float* wsf = (float*)d_ws;
    u16* n_hi   = (u16*)(wsf + 0);          // 8,388,608 u16
    u16* n_lo   = (u16*)(wsf + 4194304);
    u16* WVt_h  = (u16*)(wsf + 8388608);    // 1,048,576 u16
    u16* WVt_l  = (u16*)(wsf + 8912896);
    u16* WKt_h  = (u16*)(wsf + 9437184);    // 786,432 u16
    u16* WKt_l  = (u16*)(wsf + 9830400);
    float* Vp   = wsf + 10223616;           // 8,388,608 f32
    float* Kp   = wsf + 18612224;           // 6,291,456 f32
    float* Gb   = wsf + 24903680;           // 589,824
    float* Mb   = wsf + 25493504;           // 589,824
    float* Cb   = wsf + 26083328;           // 786,432  (end: 26,869,760 f = 102.5 MiB)
    // aliases (lifetimes disjoint, stream-ordered)
    u16* Wcmb_h  = (u16*)Vp;                // after grams
    u16* Wcmb_l  = (u16*)(Vp + 2097152);
    u16* Wfint_h = (u16*)(Vp + 4194304);
    u16* Wfint_l = (u16*)(Vp + 6291456);
    u16* WOt_h   = (u16*)Kp;                // after grams
    u16* WOt_l   = (u16*)(Kp + 524288);
    float* Fb    = Kp + 1048576;

    ln_kernel<<<BSZ * TLEN, 256, 0, stream>>>(hs, ln_g, ln_b, n_hi, n_lo);

    // WVt = WV^T (hi/lo);  Vp = normed_prefix @ WV
    transcvt<<<dim3(HHD / 32, DDIM / 32), 256, 0, stream>>>(WV, WVt_h, WVt_l, DDIM, HHD);
    gemm_mfma<0><<<dim3(HHD / 128, TLEN / 128, BSZ), 256, 0, stream>>>(
        n_hi, n_lo, (long)TLEN * DDIM, WVt_h, WVt_l, 0,
        Vp, nullptr, nullptr, (long)TLEN * HHD,
        TLEN, HHD, DDIM, pl_ptr, nullptr);

    for (int k = 0; k < NKOPS; ++k) {
        transcvt<<<dim3(HR / 32, DDIM / 32), 256, 0, stream>>>(
            WK + (size_t)k * DDIM * HR, WKt_h, WKt_l, DDIM, HR);
        gemm_mfma<0><<<dim3(HR / 128, TLEN / 128, BSZ), 256, 0, stream>>>(
            n_hi, n_lo, (long)TLEN * DDIM, WKt_h, WKt_l, 0,
            Kp, nullptr, nullptr, (long)TLEN * HR,
            TLEN, HR, DDIM, pl_ptr, nullptr);
        gram_kernel<<<dim3(NH, BSZ), 256, 0, stream>>>(Kp, Vp, Gb, Mb, Cb, k, pl_ptr);
    }

    // WOt = WO^T (into Kp region, now dead)
    transcvt<<<dim3(DDIM / 32, HHD / 32), 256, 0, stream>>>(WO, WOt_h, WOt_l, HHD, DDIM);

    solver_kernel<<<NKOPS * BSZ * NH, 256, 0, stream>>>(Gb, Mb, Cb, Fb, log_ridges, log_gammas);

    wcmb_kernel<<<dim3(DDIM / 64, NH, BSZ), 256, 0, stream>>>(WQ, Fb, gate_alphas, Wcmb_h, Wcmb_l);

    // Wfint[b] = WO^T @ Wcmb[b]^T  == Wfin[b]^T, written bf16 hi/lo row-major
    gemm_mfma<1><<<dim3(DDIM / 128, DDIM / 128, BSZ), 256, 0, stream>>>(
        WOt_h, WOt_l, 0, Wcmb_h, Wcmb_l, (long)DDIM * HHD,
        nullptr, Wfint_h, Wfint_l, (long)DDIM * DDIM,
        DDIM, DDIM, HHD, nullptr, nullptr);

    // out[b] = sigmoid(gate_alpha) * normed[b] @ Wfin[b]
    gemm_mfma<0><<<dim3(DDIM / 128, TLEN / 128, BSZ), 256, 0, stream>>>(
        n_hi, n_lo, (long)TLEN * DDIM, Wfint_h, Wfint_l, (long)DDIM * DDIM,
        out, nullptr, nullptr, (long)TLEN * DDIM,
        TLEN, DDIM, DDIM, nullptr, gate_alpha);
}

// Round 4
// 1295.164 us; speedup vs baseline: 1.9822x; 1.2407x over previous
//
#include <hip/hip_runtime.h>
#include <math.h>

typedef unsigned short u16;
typedef __attribute__((ext_vector_type(8))) short bf16x8;
typedef __attribute__((ext_vector_type(4))) float f32x4;

#define BSZ 4
#define TLEN 2048
#define DDIM 1024
#define NH 16
#define HDIM 64
#define NKOPS 4
#define RDIM 48
#define HR 768     // NH*RDIM
#define HHD 1024   // NH*HDIM
#define LNEPS 1e-5f
#define GSPLIT 4
#define GCHUNK 512

#define AS1 __attribute__((address_space(1)))
#define AS3 __attribute__((address_space(3)))

static __device__ __forceinline__ void gload16(const u16* g, u16* l) {
    __builtin_amdgcn_global_load_lds((const AS1 unsigned int*)g, (AS3 unsigned int*)l, 16, 0, 0);
}

static __device__ __forceinline__ int clamp_pl(int p) {
    if (p < 1) p = 1;
    if (p > TLEN - 1) p = TLEN - 1;
    return p;
}

static __device__ __forceinline__ u16 f2bf(float x) {
    unsigned u = __float_as_uint(x);
    return (u16)((u + 0x7FFFu + ((u >> 16) & 1u)) >> 16);
}
static __device__ __forceinline__ float bf2f(u16 h) {
    return __uint_as_float(((unsigned)h) << 16);
}

#define WB() __builtin_amdgcn_wave_barrier()

// ---------------- LayerNorm -> bf16 hi/lo split ----------------
__global__ __launch_bounds__(256) void ln_kernel(const float* __restrict__ hs,
                                                 const float* __restrict__ g,
                                                 const float* __restrict__ b,
                                                 u16* __restrict__ nh,
                                                 u16* __restrict__ nl)
{
    int row = blockIdx.x;
    int tid = threadIdx.x;
    const float* x = hs + (size_t)row * DDIM;
    float4 v = ((const float4*)x)[tid];
    float s  = v.x + v.y + v.z + v.w;
    float ss = v.x*v.x + v.y*v.y + v.z*v.z + v.w*v.w;
    for (int off = 32; off > 0; off >>= 1) {
        s  += __shfl_down(s, off);
        ss += __shfl_down(ss, off);
    }
    __shared__ float rs[4], rss[4], st[2];
    int wid = tid >> 6, lane = tid & 63;
    if (lane == 0) { rs[wid] = s; rss[wid] = ss; }
    __syncthreads();
    if (tid == 0) {
        float S  = rs[0] + rs[1] + rs[2] + rs[3];
        float SS = rss[0] + rss[1] + rss[2] + rss[3];
        float mu = S / (float)DDIM;
        float var = SS / (float)DDIM - mu * mu;
        st[0] = mu;
        st[1] = rsqrtf(var + LNEPS);
    }
    __syncthreads();
    float mu = st[0], rstd = st[1];
    float4 gv = ((const float4*)g)[tid];
    float4 bv = ((const float4*)b)[tid];
    float o[4];
    o[0] = (v.x - mu) * rstd * gv.x + bv.x;
    o[1] = (v.y - mu) * rstd * gv.y + bv.y;
    o[2] = (v.z - mu) * rstd * gv.z + bv.z;
    o[3] = (v.w - mu) * rstd * gv.w + bv.w;
    u16 h[4], l[4];
#pragma unroll
    for (int i = 0; i < 4; ++i) {
        h[i] = f2bf(o[i]);
        l[i] = f2bf(o[i] - bf2f(h[i]));
    }
    uint2 ph, pl2;
    ph.x = (unsigned)h[0] | ((unsigned)h[1] << 16);
    ph.y = (unsigned)h[2] | ((unsigned)h[3] << 16);
    pl2.x = (unsigned)l[0] | ((unsigned)l[1] << 16);
    pl2.y = (unsigned)l[2] | ((unsigned)l[3] << 16);
    *(uint2*)(nh + (size_t)row * DDIM + tid * 4) = ph;
    *(uint2*)(nl + (size_t)row * DDIM + tid * 4) = pl2;
}

// ---------------- transpose + bf16 hi/lo convert: in[R][C] f32 -> out[C][R] ----------------
__global__ __launch_bounds__(256) void transcvt(const float* __restrict__ in,
                                                u16* __restrict__ oh,
                                                u16* __restrict__ ol,
                                                int R, int C)
{
    __shared__ float t[32][33];
    int bx = blockIdx.x, by = blockIdx.y;
    int tx = threadIdx.x & 31, ty = threadIdx.x >> 5;
#pragma unroll
    for (int j = 0; j < 4; ++j)
        t[ty + j * 8][tx] = in[(size_t)(by * 32 + ty + j * 8) * C + bx * 32 + tx];
    __syncthreads();
#pragma unroll
    for (int j = 0; j < 4; ++j) {
        float v = t[tx][ty + j * 8];
        u16 h = f2bf(v);
        size_t o = (size_t)(bx * 32 + ty + j * 8) * R + by * 32 + tx;
        oh[o] = h;
        ol[o] = f2bf(v - bf2f(h));
    }
}

// ---------------- split-bf16 MFMA GEMM (NT): C[z] = A[z] @ Bt[z]^T ----------------
// A: [M][K] bf16 hi/lo, Bt: [N][K] bf16 hi/lo. 128x128 tile, BK=32, 4 waves.
// Staging via global_load_lds width=16; LDS linear [2][128][32] with XOR slot swizzle
// slot' = kg ^ ((row>>1)&3) applied on BOTH the pre-swizzled global source and the read.
// OMODE 0: f32 C out (optional sigmoid(gate) scale). OMODE 1: bf16 hi/lo out (row-major).
template<int OMODE>
__global__ __launch_bounds__(256) void gemm_mfma(
    const u16* __restrict__ Ah, const u16* __restrict__ Al, long sAz,
    const u16* __restrict__ Bth, const u16* __restrict__ Btl, long sBz,
    float* __restrict__ C, u16* __restrict__ Oh, u16* __restrict__ Ol, long sCz,
    int M, int N, int K,
    const int* __restrict__ pl_ptr, const float* __restrict__ gate_ptr)
{
    int z = blockIdx.z;
    int m0 = blockIdx.y * 128, n0 = blockIdx.x * 128;
    if (pl_ptr) {
        int p = clamp_pl(pl_ptr[0]);
        if (m0 >= (p < M ? p : M)) return;
    }
    Ah  += (size_t)z * sAz;  Al  += (size_t)z * sAz;
    Bth += (size_t)z * sBz;  Btl += (size_t)z * sBz;

    __shared__ u16 As[2][128][32];
    __shared__ u16 Bs[2][128][32];

    int tid = threadIdx.x;
    int wid = tid >> 6, ln = tid & 63;
    int wm = (wid >> 1) * 64, wn = (wid & 1) * 64;
    int r16 = ln & 15, kg = ln >> 4;

    // staging geometry: wave stages rows [rb, rb+32) of both tiles, 2 issues of 16 rows each
    int rb = wid * 32;
    int lr = ln >> 2;          // row within 16-row issue
    int sl = ln & 3;           // LDS 16B slot within the 64B row
    int koff = (sl ^ (((rb + lr) >> 1) & 3)) * 8;   // pre-swizzled global k element offset

    const u16* gA0h = Ah  + (size_t)(m0 + rb + lr) * K + koff;
    const u16* gA1h = gA0h + (size_t)16 * K;
    const u16* gA0l = Al  + (size_t)(m0 + rb + lr) * K + koff;
    const u16* gA1l = gA0l + (size_t)16 * K;
    const u16* gB0h = Bth + (size_t)(n0 + rb + lr) * K + koff;
    const u16* gB1h = gB0h + (size_t)16 * K;
    const u16* gB0l = Btl + (size_t)(n0 + rb + lr) * K + koff;
    const u16* gB1l = gB0l + (size_t)16 * K;

    u16* lA0h = &As[0][rb][0];      u16* lA1h = &As[0][rb + 16][0];
    u16* lA0l = &As[1][rb][0];      u16* lA1l = &As[1][rb + 16][0];
    u16* lB0h = &Bs[0][rb][0];      u16* lB1h = &Bs[0][rb + 16][0];
    u16* lB0l = &Bs[1][rb][0];      u16* lB1l = &Bs[1][rb + 16][0];

    f32x4 acc[4][4];
#pragma unroll
    for (int mt = 0; mt < 4; ++mt)
#pragma unroll
        for (int nt = 0; nt < 4; ++nt)
            acc[mt][nt] = (f32x4){0.f, 0.f, 0.f, 0.f};

    for (int k0 = 0; k0 < K; k0 += 32) {
        __syncthreads();                       // prior MFMA reads of LDS complete
        gload16(gA0h, lA0h);  gload16(gA1h, lA1h);
        gload16(gA0l, lA0l);  gload16(gA1l, lA1l);
        gload16(gB0h, lB0h);  gload16(gB1h, lB1h);
        gload16(gB0l, lB0l);  gload16(gB1l, lB1l);
        gA0h += 32; gA1h += 32; gA0l += 32; gA1l += 32;
        gB0h += 32; gB1h += 32; gB0l += 32; gB1l += 32;
        __syncthreads();                       // vmcnt(0) drained by compiler before barrier

        bf16x8 bhf[4], blf[4];
#pragma unroll
        for (int nt = 0; nt < 4; ++nt) {
            int r = wn + nt * 16 + r16;
            int s = (kg ^ ((r >> 1) & 3)) * 8;
            bhf[nt] = *(const bf16x8*)&Bs[0][r][s];
            blf[nt] = *(const bf16x8*)&Bs[1][r][s];
        }
#pragma unroll
        for (int mt = 0; mt < 4; ++mt) {
            int r = wm + mt * 16 + r16;
            int s = (kg ^ ((r >> 1) & 3)) * 8;
            bf16x8 ah = *(const bf16x8*)&As[0][r][s];
            bf16x8 al = *(const bf16x8*)&As[1][r][s];
#pragma unroll
            for (int nt = 0; nt < 4; ++nt) {
                acc[mt][nt] = __builtin_amdgcn_mfma_f32_16x16x32_bf16(ah, bhf[nt], acc[mt][nt], 0, 0, 0);
                acc[mt][nt] = __builtin_amdgcn_mfma_f32_16x16x32_bf16(ah, blf[nt], acc[mt][nt], 0, 0, 0);
                acc[mt][nt] = __builtin_amdgcn_mfma_f32_16x16x32_bf16(al, bhf[nt], acc[mt][nt], 0, 0, 0);
            }
        }
    }

    // C/D layout (m89/m91-verified): col = lane&15, row = (lane>>4)*4 + reg
    int orow0 = m0 + wm + kg * 4;
    int ocol0 = n0 + wn + r16;
    if (OMODE == 0) {
        float scale = 1.0f;
        if (gate_ptr) scale = 1.0f / (1.0f + expf(-gate_ptr[0]));
        float* Cz = C + (size_t)z * sCz;
#pragma unroll
        for (int mt = 0; mt < 4; ++mt)
#pragma unroll
            for (int nt = 0; nt < 4; ++nt)
#pragma unroll
                for (int j = 0; j < 4; ++j)
                    Cz[(size_t)(orow0 + mt * 16 + j) * N + ocol0 + nt * 16] = acc[mt][nt][j] * scale;
    } else {
        u16* Ohz = Oh + (size_t)z * sCz;
        u16* Olz = Ol + (size_t)z * sCz;
#pragma unroll
        for (int mt = 0; mt < 4; ++mt)
#pragma unroll
            for (int nt = 0; nt < 4; ++nt)
#pragma unroll
                for (int j = 0; j < 4; ++j) {
                    float v = acc[mt][nt][j];
                    u16 h = f2bf(v);
                    size_t o = (size_t)(orow0 + mt * 16 + j) * N + ocol0 + nt * 16;
                    Ohz[o] = h;
                    Olz[o] = f2bf(v - bf2f(h));
                }
    }
}

// ---------------- Gram statistics, 4-way time-split partials ----------------
// grid (NH, BSZ, GSPLIT). Partial sums for chunk [sp*512, min(sp*512+512, pl)).
__global__ __launch_bounds__(256) void gram_kernel(const float* __restrict__ Kp,
                                                   const float* __restrict__ Vp,
                                                   float* __restrict__ Gpart,
                                                   float* __restrict__ Mpart,
                                                   float* __restrict__ Cpart,
                                                   const int* __restrict__ pl_ptr)
{
    int h = blockIdx.x, b = blockIdx.y, sp = blockIdx.z;
    int pl = clamp_pl(pl_ptr[0]);
    int lo = sp * GCHUNK;
    int hi = lo + GCHUNK; if (hi > pl) hi = pl;
    __shared__ float pks[65][48];
    __shared__ float pvs[64][64];
    int tid = threadIdx.x;
    int tx = tid & 15, ty = tid >> 4;
    float gacc[3][3] = {}, macc[3][3] = {}, cacc[4][3] = {};
    const float* Kbase = Kp + (size_t)b * TLEN * HR + h * RDIM;
    const float* Vbase = Vp + (size_t)b * TLEN * HHD + h * HDIM;

    for (int c0 = lo; c0 < hi; c0 += 64) {
        for (int idx = tid; idx < 65 * 48; idx += 256) {
            int rr = idx / 48, cc = idx % 48;
            int tg = c0 + rr;
            pks[rr][cc] = (tg < pl) ? Kbase[(size_t)tg * HR + cc] : 0.f;
        }
        for (int idx = tid; idx < 64 * 64; idx += 256) {
            int rr = idx >> 6, cc = idx & 63;
            int tg = c0 + rr;
            pvs[rr][cc] = (tg < pl) ? Vbase[(size_t)tg * HHD + cc] : 0.f;
        }
        __syncthreads();
#pragma unroll 2
        for (int l = 0; l < 64; ++l) {
            float a0[3], a1[3], bb[3], vv[4];
#pragma unroll
            for (int i = 0; i < 3; ++i) {
                a0[i] = pks[l][tx * 3 + i];
                a1[i] = pks[l + 1][tx * 3 + i];
                bb[i] = pks[l][ty * 3 + i];
            }
#pragma unroll
            for (int j = 0; j < 4; ++j) vv[j] = pvs[l][ty * 4 + j];
#pragma unroll
            for (int i = 0; i < 3; ++i)
#pragma unroll
                for (int j = 0; j < 3; ++j) {
                    gacc[i][j] += a0[i] * bb[j];
                    macc[i][j] += a1[i] * bb[j];
                }
#pragma unroll
            for (int j = 0; j < 4; ++j)
#pragma unroll
                for (int i = 0; i < 3; ++i)
                    cacc[j][i] += vv[j] * a0[i];
        }
        __syncthreads();
    }
    size_t pbase = (size_t)sp * (BSZ * NH) + b * NH + h;
    float* Gp = Gpart + pbase * 2304;
    float* Mp = Mpart + pbase * 2304;
    float* Cp = Cpart + pbase * 3072;
#pragma unroll
    for (int i = 0; i < 3; ++i)
#pragma unroll
        for (int j = 0; j < 3; ++j) {
            Gp[(tx * 3 + i) * 48 + (ty * 3 + j)] = gacc[i][j];
            Mp[(tx * 3 + i) * 48 + (ty * 3 + j)] = macc[i][j];
        }
#pragma unroll
    for (int j = 0; j < 4; ++j)
#pragma unroll
        for (int i = 0; i < 3; ++i)
            Cp[(ty * 4 + j) * 48 + (tx * 3 + i)] = cacc[j][i];
}

// reduce GSPLIT partials into the per-k slot of Gb/Mb/Cb
__global__ __launch_bounds__(256) void gram_reduce(const float* __restrict__ Gpart,
                                                   const float* __restrict__ Mpart,
                                                   const float* __restrict__ Cpart,
                                                   float* __restrict__ Gb,
                                                   float* __restrict__ Mb,
                                                   float* __restrict__ Cb,
                                                   int k)
{
    int p = blockIdx.x;               // b*NH+h
    size_t ob = ((size_t)k * (BSZ * NH) + p);
    for (int idx = threadIdx.x; idx < 2304; idx += 256) {
        float sg = 0.f, sm = 0.f;
#pragma unroll
        for (int sp = 0; sp < GSPLIT; ++sp) {
            size_t pb = ((size_t)sp * (BSZ * NH) + p);
            sg += Gpart[pb * 2304 + idx];
            sm += Mpart[pb * 2304 + idx];
        }
        Gb[ob * 2304 + idx] = sg;
        Mb[ob * 2304 + idx] = sm;
    }
    for (int idx = threadIdx.x; idx < 3072; idx += 256) {
        float sc = 0.f;
#pragma unroll
        for (int sp = 0; sp < GSPLIT; ++sp)
            sc += Cpart[((size_t)sp * (BSZ * NH) + p) * 3072 + idx];
        Cb[ob * 3072 + idx] = sc;
    }
}

// ---------------- per-(k,b,h) solver: one problem per 64-lane wave, no s_barrier ----------------
// F = B_v * L * A_w * A_w * L^{-1}   (64 x 48)
__global__ __launch_bounds__(64) void solver_kernel(const float* __restrict__ Gb,
                                                    const float* __restrict__ Mb,
                                                    const float* __restrict__ Cb,
                                                    float* __restrict__ Fb,
                                                    const float* __restrict__ log_ridges,
                                                    const float* __restrict__ log_gammas)
{
    int blk = blockIdx.x;                 // (k*BSZ + b)*NH + h
    int k = blk / (BSZ * NH);
    int t = threadIdx.x;
    __shared__ float Ls[48 * 49];
    __shared__ float Aw[48 * 49];
    __shared__ float Sm[48 * 49];
    __shared__ float Xs[48 * 65];
    __shared__ float B2[64 * 49];
    __shared__ float pv1[48];

    size_t base = (size_t)blk;
    const float* Gp = Gb + base * 2304;
    const float* Mp = Mb + base * 2304;
    const float* Cp = Cb + base * 3072;
    float ridge = expf(log_ridges[k]);

    // load G + ridge*I
    for (int idx = t; idx < 2304; idx += 64) {
        int i = idx / 48, j = idx % 48;
        float v = Gp[idx];
        if (i == j) v += ridge;
        Ls[i * 49 + j] = v;
    }
    WB();
    // Cholesky (lane t owns row t)
    for (int j = 0; j < 48; ++j) {
        float v = 0.f;
        if (t >= j && t < 48) {
            v = Ls[t * 49 + j];
            for (int m = 0; m < j; ++m) v -= Ls[t * 49 + m] * Ls[j * 49 + m];
        }
        if (t == j) Ls[j * 49 + j] = sqrtf(fmaxf(v, 1e-30f));
        WB();
        if (t > j && t < 48) Ls[t * 49 + j] = v / Ls[j * 49 + j];
        WB();
    }
    // U = L^{-1} M  (lane t owns column t; no cross-lane deps inside)
    for (int idx = t; idx < 2304; idx += 64) Aw[(idx / 48) * 49 + (idx % 48)] = Mp[idx];
    WB();
    if (t < 48) {
        for (int i = 0; i < 48; ++i) {
            float v = Aw[i * 49 + t];
            for (int m = 0; m < i; ++m) v -= Ls[i * 49 + m] * Aw[m * 49 + t];
            Aw[i * 49 + t] = v / Ls[i * 49 + i];
        }
    }
    WB();
    // Sm = U^T ; Sm <- L^{-1} Sm ; Aw = Sm^T  (= A_w)
    for (int idx = t; idx < 2304; idx += 64) { int i = idx / 48, j = idx % 48; Sm[i * 49 + j] = Aw[j * 49 + i]; }
    WB();
    if (t < 48) {
        for (int i = 0; i < 48; ++i) {
            float v = Sm[i * 49 + t];
            for (int m = 0; m < i; ++m) v -= Ls[i * 49 + m] * Sm[m * 49 + t];
            Sm[i * 49 + t] = v / Ls[i * 49 + i];
        }
    }
    WB();
    for (int idx = t; idx < 2304; idx += 64) { int i = idx / 48, j = idx % 48; Aw[i * 49 + j] = Sm[j * 49 + i]; }
    WB();
    // Sm = Aw^T Aw
    for (int idx = t; idx < 2304; idx += 64) {
        int i = idx / 48, j = idx % 48;
        float s = 0.f;
        for (int m = 0; m < 48; ++m) s += Aw[m * 49 + i] * Aw[m * 49 + j];
        Sm[i * 49 + j] = s;
    }
    if (t < 48) pv1[t] = ((float)((t * 2654435761u) & 0xFFFF)) / 65536.0f + 0.5f;
    WB();
    // power iteration on Sm (normalize every 4)
    for (int it = 0; it < 96; ++it) {
        float s = 0.f;
        if (t < 48) {
            for (int j = 0; j < 48; ++j) s += Sm[t * 49 + j] * pv1[j];
        }
        WB();
        if ((it & 3) == 3) {
            float nn = s * s;
            for (int off = 1; off < 64; off <<= 1) nn += __shfl_xor(nn, off);
            s *= rsqrtf(fmaxf(nn, 1e-30f));
        }
        if (t < 48) pv1[t] = s;
        WB();
    }
    float lam;
    {
        float s = 0.f;
        if (t < 48) {
            for (int j = 0; j < 48; ++j) s += Sm[t * 49 + j] * pv1[j];
        }
        float nn = s * s;
        for (int off = 1; off < 64; off <<= 1) nn += __shfl_xor(nn, off);
        lam = sqrtf(nn);                       // lambda_max(S) = sigma_max^2
    }
    float sigma = sqrtf(fmaxf(lam, 0.f));
    float gamma = expf(log_gammas[k]);
    float scl = fminf(gamma, 1.f) / fmaxf(fmaxf(sigma, 1e-8f), 1.f);
    for (int idx = t; idx < 2304; idx += 64) Aw[(idx / 48) * 49 + (idx % 48)] *= scl;
    WB();
    // Bv^T = L^{-T} L^{-1} Cv^T   (lane t owns column t of Xs[48][65])
    for (int idx = t; idx < 3072; idx += 64) {
        int d = idx / 48, r = idx % 48;
        Xs[r * 65 + d] = Cp[idx];
    }
    WB();
    for (int i = 0; i < 48; ++i) {
        float v = Xs[i * 65 + t];
        for (int m = 0; m < i; ++m) v -= Ls[i * 49 + m] * Xs[m * 65 + t];
        Xs[i * 65 + t] = v / Ls[i * 49 + i];
    }
    for (int i = 47; i >= 0; --i) {
        float v = Xs[i * 65 + t];
        for (int m = i + 1; m < 48; ++m) v -= Ls[m * 49 + i] * Xs[m * 65 + t];
        Xs[i * 65 + t] = v / Ls[i * 49 + i];
    }
    WB();
    // T1 = B_v * L  -> B2   (B_v[d][m] = Xs[m*65+d])
    for (int idx = t; idx < 3072; idx += 64) {
        int d = idx / 48, j = idx % 48;
        float s = 0.f;
        for (int m = j; m < 48; ++m) s += Xs[m * 65 + d] * Ls[m * 49 + j];
        B2[d * 49 + j] = s;
    }
    WB();
    // T2 = T1 * Aw -> Xs flat [d*48+j]
    for (int idx = t; idx < 3072; idx += 64) {
        int d = idx / 48, j = idx % 48;
        float s = 0.f;
        for (int m = 0; m < 48; ++m) s += B2[d * 49 + m] * Aw[m * 49 + j];
        Xs[d * 48 + j] = s;
    }
    WB();
    // T3 = T2 * Aw -> B2
    for (int idx = t; idx < 3072; idx += 64) {
        int d = idx / 48, j = idx % 48;
        float s = 0.f;
        for (int m = 0; m < 48; ++m) s += Xs[d * 48 + m] * Aw[m * 49 + j];
        B2[d * 49 + j] = s;
    }
    WB();
    // F solves F*L = T3, lane-own row d = t, into Xs flat
    {
        int d = t;
        for (int j = 47; j >= 0; --j) {
            float s = B2[d * 49 + j];
            for (int m = j + 1; m < 48; ++m) s -= Xs[d * 48 + m] * Ls[m * 49 + j];
            Xs[d * 48 + j] = s / Ls[j * 49 + j];
        }
    }
    WB();
    for (int idx = t; idx < 3072; idx += 64) Fb[base * 3072 + idx] = Xs[idx];
}

// ---------------- W_cmb build -> bf16 hi/lo ----------------
__global__ __launch_bounds__(256) void wcmb_kernel(const float* __restrict__ WQ,
                                                   const float* __restrict__ Fb,
                                                   const float* __restrict__ gate_alphas,
                                                   u16* __restrict__ Wh,
                                                   u16* __restrict__ Wl)
{
    int dt = blockIdx.x;  // row tile (0..15)
    int h = blockIdx.y, b = blockIdx.z;
    __shared__ float wq[64][49];
    __shared__ float fs[64][49];
    int tid = threadIdx.x;
    int tx = tid & 15, ty = tid >> 4;
    float acc[4][4] = {};
    for (int k = 0; k < NKOPS; ++k) {
        float gate = 1.0f / (1.0f + expf(-gate_alphas[k]));
        for (int idx = tid; idx < 64 * 48; idx += 256) {
            int rr = idx / 48, cc = idx % 48;
            wq[rr][cc] = WQ[((size_t)k * DDIM + dt * 64 + rr) * HR + h * RDIM + cc];
            fs[rr][cc] = gate * Fb[(((size_t)k * BSZ + b) * NH + h) * 3072 + idx];
        }
        __syncthreads();
        for (int r = 0; r < 48; ++r) {
            float a[4], bb[4];
#pragma unroll
            for (int i = 0; i < 4; ++i) { a[i] = wq[tx * 4 + i][r]; bb[i] = fs[ty * 4 + i][r]; }
#pragma unroll
            for (int i = 0; i < 4; ++i)
#pragma unroll
                for (int j = 0; j < 4; ++j)
                    acc[i][j] += a[i] * bb[j];
        }
        __syncthreads();
    }
#pragma unroll
    for (int i = 0; i < 4; ++i)
#pragma unroll
        for (int j = 0; j < 4; ++j) {
            size_t o = ((size_t)b * DDIM + dt * 64 + tx * 4 + i) * HHD + h * HDIM + ty * 4 + j;
            float v = acc[i][j];
            u16 hh = f2bf(v);
            Wh[o] = hh;
            Wl[o] = f2bf(v - bf2f(hh));
        }
}

// ---------------- host launch ----------------
extern "C" void kernel_launch(void* const* d_in, const int* in_sizes, int n_in,
                              void* d_out, int out_size, void* d_ws, size_t ws_size,
                              hipStream_t stream)
{
    const float* hs          = (const float*)d_in[0];
    const float* WK          = (const float*)d_in[1];
    const float* WQ          = (const float*)d_in[2];
    const float* WV          = (const float*)d_in[3];
    const float* WO          = (const float*)d_in[4];
    const float* ln_g        = (const float*)d_in[5];
    const float* ln_b        = (const float*)d_in[6];
    const float* gate_alphas = (const float*)d_in[7];
    const float* gate_alpha  = (const float*)d_in[8];
    const float* log_ridges  = (const float*)d_in[9];
    const float* log_gammas  = (const float*)d_in[10];
    const int*   pl_ptr      = (const int*)d_in[11];
    float* out = (float*)d_out;

    float* wsf = (float*)d_ws;
    u16* n_hi   = (u16*)(wsf + 0);          // 8,388,608 u16
    u16* n_lo   = (u16*)(wsf + 4194304);
    u16* WVt_h  = (u16*)(wsf + 8388608);    // 1,048,576 u16
    u16* WVt_l  = (u16*)(wsf + 8912896);
    u16* WKt_h  = (u16*)(wsf + 9437184);    // 786,432 u16
    u16* WKt_l  = (u16*)(wsf + 9830400);
    float* Vp   = wsf + 10223616;           // 8,388,608 f32
    float* Kp   = wsf + 18612224;           // 6,291,456 f32
    float* Gb   = wsf + 24903680;           // 589,824
    float* Mb   = wsf + 25493504;           // 589,824
    float* Cb   = wsf + 26083328;           // 786,432  (end: 26,869,760 f = 102.5 MiB)
    // aliases (lifetimes disjoint, stream-ordered)
    u16* Wcmb_h  = (u16*)Vp;                // after grams
    u16* Wcmb_l  = (u16*)(Vp + 2097152);
    u16* Wfint_h = (u16*)(Vp + 4194304);
    u16* Wfint_l = (u16*)(Vp + 6291456);
    u16* WOt_h   = (u16*)Kp;                // after grams
    u16* WOt_l   = (u16*)(Kp + 524288);
    float* Fb    = Kp + 1048576;
    // gram partials live in d_out (dead before final GEMM overwrites all of d_out)
    float* Gpart = out;                     // 589,824
    float* Mpart = out + 589824;            // 589,824
    float* Cpart = out + 1179648;           // 786,432  (end 1,966,080 < 8,388,608)

    ln_kernel<<<BSZ * TLEN, 256, 0, stream>>>(hs, ln_g, ln_b, n_hi, n_lo);

    // WVt = WV^T (hi/lo);  Vp = normed_prefix @ WV
    transcvt<<<dim3(HHD / 32, DDIM / 32), 256, 0, stream>>>(WV, WVt_h, WVt_l, DDIM, HHD);
    gemm_mfma<0><<<dim3(HHD / 128, TLEN / 128, BSZ), 256, 0, stream>>>(
        n_hi, n_lo, (long)TLEN * DDIM, WVt_h, WVt_l, 0,
        Vp, nullptr, nullptr, (long)TLEN * HHD,
        TLEN, HHD, DDIM, pl_ptr, nullptr);

    for (int k = 0; k < NKOPS; ++k) {
        transcvt<<<dim3(HR / 32, DDIM / 32), 256, 0, stream>>>(
            WK + (size_t)k * DDIM * HR, WKt_h, WKt_l, DDIM, HR);
        gemm_mfma<0><<<dim3(HR / 128, TLEN / 128, BSZ), 256, 0, stream>>>(
            n_hi, n_lo, (long)TLEN * DDIM, WKt_h, WKt_l, 0,
            Kp, nullptr, nullptr, (long)TLEN * HR,
            TLEN, HR, DDIM, pl_ptr, nullptr);
        gram_kernel<<<dim3(NH, BSZ, GSPLIT), 256, 0, stream>>>(Kp, Vp, Gpart, Mpart, Cpart, pl_ptr);
        gram_reduce<<<BSZ * NH, 256, 0, stream>>>(Gpart, Mpart, Cpart, Gb, Mb, Cb, k);
    }

    // WOt = WO^T (into Kp region, now dead)
    transcvt<<<dim3(DDIM / 32, HHD / 32), 256, 0, stream>>>(WO, WOt_h, WOt_l, HHD, DDIM);

    solver_kernel<<<NKOPS * BSZ * NH, 64, 0, stream>>>(Gb, Mb, Cb, Fb, log_ridges, log_gammas);

    wcmb_kernel<<<dim3(DDIM / 64, NH, BSZ), 256, 0, stream>>>(WQ, Fb, gate_alphas, Wcmb_h, Wcmb_l);

    // Wfint[b] = WO^T @ Wcmb[b]^T  == Wfin[b]^T, written bf16 hi/lo row-major
    gemm_mfma<1><<<dim3(DDIM / 128, DDIM / 128, BSZ), 256, 0, stream>>>(
        WOt_h, WOt_l, 0, Wcmb_h, Wcmb_l, (long)DDIM * HHD,
        nullptr, Wfint_h, Wfint_l, (long)DDIM * DDIM,
        DDIM, DDIM, HHD, nullptr, nullptr);

    // out[b] = sigmoid(gate_alpha) * normed[b] @ Wfin[b]
    gemm_mfma<0><<<dim3(DDIM / 128, TLEN / 128, BSZ), 256, 0, stream>>>(
        n_hi, n_lo, (long)TLEN * DDIM, Wfint_h, Wfint_l, (long)DDIM * DDIM,
        out, nullptr, nullptr, (long)TLEN * DDIM,
        TLEN, DDIM, DDIM, nullptr, gate_alpha);
}